// Round 1
// baseline (148.939 us; speedup 1.0000x reference)
//
#include <hip/hip_runtime.h>

#define ROWS 256  // rows per block == blockDim.x

// Force a wave-uniform value into an SGPR (valid because weights are uniform).
__device__ __forceinline__ float uni(float v) {
    return __int_as_float(__builtin_amdgcn_readfirstlane(__float_as_int(v)));
}

// tanh(x) = 1 - 2/(1 + exp(2x));  exp(2x) = exp2(x * 2*log2(e))
__device__ __forceinline__ float fast_tanh(float x) {
    float e = __builtin_amdgcn_exp2f(x * 2.885390081777927f);
    float r = __builtin_amdgcn_rcpf(e + 1.0f);
    return fmaf(-2.0f, r, 1.0f);
}

__global__ __launch_bounds__(ROWS)
void recpolicy_kernel(const float* __restrict__ x,
                      const float* __restrict__ Wih_up,
                      const float* __restrict__ Whh_up,
                      const float* __restrict__ bih_up,
                      const float* __restrict__ bhh_up,
                      const float* __restrict__ W1,
                      const float* __restrict__ b1,
                      const float* __restrict__ W2,
                      const float* __restrict__ b2,
                      const float* __restrict__ Wih_dn,
                      const float* __restrict__ Whh_dn,
                      const float* __restrict__ bih_dn,
                      const float* __restrict__ bhh_dn,
                      const float* __restrict__ Wo,
                      const float* __restrict__ bo,
                      float* __restrict__ out)
{
    __shared__ float xs[ROWS * 19];  // 256 rows x 18, padded to 19 (odd stride)
    const int tid = threadIdx.x;
    const long long row0 = (long long)blockIdx.x * ROWS;

    // ---- stage 256 rows x 18 f32 = 2304 float2, coalesced ----
    const float2* xg2 = (const float2*)(x + row0 * 18);
    #pragma unroll
    for (int k = 0; k < 9; ++k) {
        int idx2 = k * ROWS + tid;          // 0..2303
        float2 v = xg2[idx2];
        int r = idx2 / 9;                   // row (18 floats = 9 float2 per row)
        int c = (idx2 - r * 9) * 2;         // even column; pair never crosses a row
        xs[r * 19 + c]     = v.x;
        xs[r * 19 + c + 1] = v.y;
    }

    // ---- weights -> SGPRs (uniform) ----
    float wihu[8], whhu[16], bu[4];
    #pragma unroll
    for (int i = 0; i < 8; ++i) wihu[i] = uni(Wih_up[i]);
    #pragma unroll
    for (int i = 0; i < 16; ++i) whhu[i] = uni(Whh_up[i]);
    #pragma unroll
    for (int i = 0; i < 4; ++i) bu[i] = uni(bih_up[i] + bhh_up[i]);

    float w1[32], bb1[4], w2[16], bb2[4];
    #pragma unroll
    for (int i = 0; i < 32; ++i) w1[i] = uni(W1[i]);
    #pragma unroll
    for (int i = 0; i < 4; ++i) bb1[i] = uni(b1[i]);
    #pragma unroll
    for (int i = 0; i < 16; ++i) w2[i] = uni(W2[i]);
    #pragma unroll
    for (int i = 0; i < 4; ++i) bb2[i] = uni(b2[i]);

    float wihd[16], whhd[16], bd[4], wo[5], bO;
    #pragma unroll
    for (int i = 0; i < 16; ++i) wihd[i] = uni(Wih_dn[i]);
    #pragma unroll
    for (int i = 0; i < 16; ++i) whhd[i] = uni(Whh_dn[i]);
    #pragma unroll
    for (int i = 0; i < 4; ++i) bd[i] = uni(bih_dn[i] + bhh_dn[i]);
    #pragma unroll
    for (int i = 0; i < 5; ++i) wo[i] = uni(Wo[i]);
    bO = uni(bo[0]);

    __syncthreads();

    // ---- per-row compute ----
    const float* xr = &xs[tid * 19];
    float obs[4], j[7], jd[7];
    #pragma unroll
    for (int i = 0; i < 4; ++i) obs[i] = xr[i];
    #pragma unroll
    for (int i = 0; i < 7; ++i) j[i] = xr[4 + i];
    #pragma unroll
    for (int i = 0; i < 7; ++i) jd[i] = xr[11 + i];

    // up scan: t = 6 .. 0 (reversed sequence), store h at each t
    float h[4] = {0.f, 0.f, 0.f, 0.f};
    float hup[7][4];
    #pragma unroll
    for (int t = 6; t >= 0; --t) {
        float pre[4];
        #pragma unroll
        for (int i = 0; i < 4; ++i) {
            float a = bu[i];
            a = fmaf(j[t],  wihu[i * 2 + 0], a);
            a = fmaf(jd[t], wihu[i * 2 + 1], a);
            #pragma unroll
            for (int k = 0; k < 4; ++k) a = fmaf(h[k], whhu[i * 4 + k], a);
            pre[i] = a;
        }
        #pragma unroll
        for (int i = 0; i < 4; ++i) { h[i] = fast_tanh(pre[i]); hup[t][i] = h[i]; }
    }
    // h == h_last == hup[0]

    // head: h0 = tanh(W2 @ tanh(W1 @ [obs, h_last] + b1) + b2)
    float g[4];
    #pragma unroll
    for (int i = 0; i < 4; ++i) {
        float a = bb1[i];
        #pragma unroll
        for (int k = 0; k < 4; ++k) a = fmaf(obs[k], w1[i * 8 + k], a);
        #pragma unroll
        for (int k = 0; k < 4; ++k) a = fmaf(h[k],   w1[i * 8 + 4 + k], a);
        g[i] = fast_tanh(a);
    }
    #pragma unroll
    for (int i = 0; i < 4; ++i) {
        float a = bb2[i];
        #pragma unroll
        for (int k = 0; k < 4; ++k) a = fmaf(g[k], w2[i * 4 + k], a);
        h[i] = fast_tanh(a);
    }

    // down scan: t = 0 .. 6; act uses h BEFORE update
    float act[7];
    #pragma unroll
    for (int t = 0; t < 7; ++t) {
        float a = bO;
        #pragma unroll
        for (int k = 0; k < 4; ++k) a = fmaf(h[k], wo[k], a);
        a = fmaf(j[t], wo[4], a);
        act[t] = a;
        float pre[4];
        #pragma unroll
        for (int i = 0; i < 4; ++i) {
            float s = bd[i];
            #pragma unroll
            for (int k = 0; k < 4; ++k) s = fmaf(hup[t][k], wihd[i * 4 + k], s);
            #pragma unroll
            for (int k = 0; k < 4; ++k) s = fmaf(h[k],      whhd[i * 4 + k], s);
            pre[i] = s;
        }
        #pragma unroll
        for (int i = 0; i < 4; ++i) h[i] = fast_tanh(pre[i]);  // t==6 update is dead-code-eliminated
    }

    // ---- stage output in LDS (reuse xs), then coalesced store ----
    __syncthreads();
    float* os = xs;  // needs 256*7 = 1792 floats, fits in 256*19
    #pragma unroll
    for (int t = 0; t < 7; ++t) os[tid * 7 + t] = act[t];
    __syncthreads();
    float* og = out + row0 * 7;
    #pragma unroll
    for (int k = 0; k < 7; ++k) og[k * ROWS + tid] = os[k * ROWS + tid];
}

extern "C" void kernel_launch(void* const* d_in, const int* in_sizes, int n_in,
                              void* d_out, int out_size, void* d_ws, size_t ws_size,
                              hipStream_t stream) {
    const float* x      = (const float*)d_in[0];
    const float* Wih_up = (const float*)d_in[1];
    const float* Whh_up = (const float*)d_in[2];
    const float* bih_up = (const float*)d_in[3];
    const float* bhh_up = (const float*)d_in[4];
    const float* W1     = (const float*)d_in[5];
    const float* b1     = (const float*)d_in[6];
    const float* W2     = (const float*)d_in[7];
    const float* b2     = (const float*)d_in[8];
    const float* Wih_dn = (const float*)d_in[9];
    const float* Whh_dn = (const float*)d_in[10];
    const float* bih_dn = (const float*)d_in[11];
    const float* bhh_dn = (const float*)d_in[12];
    const float* Wo     = (const float*)d_in[13];
    const float* bo     = (const float*)d_in[14];
    float* out = (float*)d_out;

    const int Btot = in_sizes[0] / 18;   // 1048576
    const int blocks = Btot / ROWS;      // 4096

    recpolicy_kernel<<<blocks, ROWS, 0, stream>>>(
        x, Wih_up, Whh_up, bih_up, bhh_up, W1, b1, W2, b2,
        Wih_dn, Whh_dn, bih_dn, bhh_dn, Wo, bo, out);
}